// Round 2
// baseline (1226.909 us; speedup 1.0000x reference)
//
#include <hip/hip_runtime.h>
#include <hip/hip_bf16.h>
#include <hip/hip_fp16.h>

// ---------------------------------------------------------------------------
// GCN forward: 4x (gemm -> sym-norm aggregate -> +b -> relu), scalar 5th conv,
// mean-pool heads, masked softmax.
//
// R1..R12: see history (MFMA fp16 gemms, bucketed CSR, half2 lane-split
//     gather, fused layer-4 agg, single-pass softmax). 531 us.
// R13: col-blocked pass-synchronized gather (7 col-blocks of 16384 nodes =
//     2MB of Ys each, fits one XCD 4MiB L2; persistent waves, NPW=25 nodes
//     in register acc, all waves sweep block b simultaneously). FAILED:
//     inner gather loops had half-dependent BOUNDS -> the two 32-lane halves
//     diverged -> __shfl executed half-active, reading inactive-lane sources
//     (undefined on CDNA). probs passed (loose), v-head off by 1e-4.
// R14: same structure, gather loops restored to R12's wave-uniform form:
//     uniform bounds, per-lane shfl INDEX (j+half), guard only the
//     accumulate. Every shfl is executed by all 64 lanes.
// ---------------------------------------------------------------------------

#define WAVE 64
#define BSHIFT 9
#define BROWS 512           // rows per bucket
#define ACHUNK 8192         // edges per bin_edges block
#define CAP 17408           // bucket capacity (mean 16327, sigma ~128)
#define NBLK 8              // col-blocks (blocks 0..6 used for N=100000)
#define BLKSHIFT 14         // 16384 cols per block -> 2MB of Ys per block
#define NPW 25              // nodes per wave in agg kernels

using half8  = __attribute__((ext_vector_type(8))) _Float16;
using float4v = __attribute__((ext_vector_type(4))) float;

// ---------------- small helpers ----------------
__device__ __forceinline__ float waveSum(float v) {
  #pragma unroll
  for (int o = 32; o; o >>= 1) v += __shfl_xor(v, o);
  return v;
}
__device__ __forceinline__ float waveMax(float v) {
  #pragma unroll
  for (int o = 32; o; o >>= 1) v = fmaxf(v, __shfl_xor(v, o));
  return v;
}

// ---------------- bucket init: fixed-capacity bump-allocator seeds ----------
__global__ void bucket_init(int* __restrict__ bucket_fill, int nbkt) {
  int b = blockIdx.x * blockDim.x + threadIdx.x;
  if (b < nbkt) bucket_fill[b] = b * CAP;
}

// ---------------- bin edges into bucket-major packed array ----------------
// packed edge: (local_row 9b) << 17 | col (17b)   [N < 131072]
__global__ __launch_bounds__(256) void bin_edges(const int* __restrict__ ei,
                                                 int* __restrict__ bucket_fill,
                                                 int* __restrict__ eb, int E) {
  __shared__ int hist[256], basee[256], rank[256];
  int t = threadIdx.x;
  hist[t] = 0; rank[t] = 0;
  __syncthreads();
  int c0 = blockIdx.x * ACHUNK;
  #pragma unroll
  for (int k = 0; k < ACHUNK / 256; ++k) {
    int e = c0 + k * 256 + t;
    if (e < E) atomicAdd(&hist[ei[e] >> BSHIFT], 1);
  }
  __syncthreads();
  if (hist[t]) basee[t] = atomicAdd(&bucket_fill[t], hist[t]);
  __syncthreads();
  #pragma unroll
  for (int k = 0; k < ACHUNK / 256; ++k) {
    int e = c0 + k * 256 + t;
    if (e < E) {
      int r = ei[e], c = ei[E + e];
      int bb = r >> BSHIFT;
      int p = basee[bb] + atomicAdd(&rank[bb], 1);
      eb[p] = ((r & (BROWS - 1)) << 17) | c;
    }
  }
}

// ---------------- per-bucket CSR finalize: (row, col-block) two-level sort --
// E0 = b*CAP; E1 = bucket_fill[b]. Output: col_s grouped by row then by
// col-block; row_bp[i*8+q] = start of (row i, block q); row end = bp[i*8+7]
// (block 7 is always empty since col < 114688).
__global__ __launch_bounds__(256) void csr_bucket(const int* __restrict__ eb,
                                                  const int* __restrict__ bucket_fill,
                                                  int* __restrict__ row_bp,
                                                  float* __restrict__ dinv,
                                                  int* __restrict__ col_s, int N) {
  __shared__ int deg[BROWS * NBLK];   // 4096: counts, then exclusive prefix
  __shared__ int fill[BROWS * NBLK];
  __shared__ int sh[256];
  int b = blockIdx.x;
  int base = b << BSHIFT;
  int R = min(BROWS, N - base);
  int t = threadIdx.x;
  for (int q = t; q < BROWS * NBLK; q += 256) { deg[q] = 0; fill[q] = 0; }
  __syncthreads();
  int E0 = b * CAP, E1 = bucket_fill[b];
  int tot = E1 - E0;
  for (int e = E0 + t; e < E1; e += 256) {
    int v = eb[e];
    atomicAdd(&deg[(v >> 17) * NBLK + ((v & 0x1FFFF) >> BLKSHIFT)], 1);
  }
  __syncthreads();
  // exclusive prefix over 4096 cells (row-major: row, block). t owns 16 cells.
  int loc[16];
  int s = 0;
  #pragma unroll
  for (int q = 0; q < 16; ++q) { loc[q] = s; s += deg[t * 16 + q]; }
  sh[t] = s;
  __syncthreads();
  for (int o = 1; o < 256; o <<= 1) {
    int x = (t >= o) ? sh[t - o] : 0;
    __syncthreads();
    sh[t] += x;
    __syncthreads();
  }
  int ex = sh[t] - s;
  #pragma unroll
  for (int q = 0; q < 16; ++q) deg[t * 16 + q] = ex + loc[q];   // -> prefix
  __syncthreads();
  for (int i = t; i < R; i += 256) {
    int st = deg[i * NBLK];
    int en = (i == BROWS - 1) ? tot : deg[(i + 1) * NBLK];
    dinv[base + i] = rsqrtf((float)(en - st + 1));    // +1 self-loop
    #pragma unroll
    for (int q = 0; q < NBLK; ++q)
      row_bp[(size_t)(base + i) * NBLK + q] = E0 + deg[i * NBLK + q];
  }
  for (int e = E0 + t; e < E1; e += 256) {
    int v = eb[e];
    int c = v & 0x1FFFF;
    int cell = (v >> 17) * NBLK + (c >> BLKSHIFT);
    int p = E0 + deg[cell] + atomicAdd(&fill[cell], 1);
    col_s[p] = c;
  }
}

// ---------------- MFMA GEMM: Y[N][64] = fp16(dinv (.) (A[N][K] @ W[K][64]))
template <int K, bool A32>
__global__ __launch_bounds__(256) void gemm_f16(const void* __restrict__ Ain,
                                                const float* __restrict__ Wg,
                                                const float* __restrict__ dinv,
                                                __half* __restrict__ Y, int N) {
  __shared__ _Float16 Wt[64][K + 8];
  int t = threadIdx.x;
  for (int idx = t; idx < K * 64; idx += 256) {
    int k = idx >> 6, n = idx & 63;
    Wt[n][k] = (_Float16)Wg[idx];
  }
  __syncthreads();
  int wave = t >> 6, lane = t & 63;
  int m = lane & 15, quad = lane >> 4;
  int r0 = blockIdx.x * 64 + wave * 16;
  float4v acc0 = {0.f, 0.f, 0.f, 0.f}, acc1 = {0.f, 0.f, 0.f, 0.f};
  float4v acc2 = {0.f, 0.f, 0.f, 0.f}, acc3 = {0.f, 0.f, 0.f, 0.f};
  int gr = r0 + m;
  bool valid = gr < N;
  int grs = valid ? gr : 0;
  const half8* arow = (const half8*)((const _Float16*)Ain + (size_t)grs * K);
  const float4* arow32 = (const float4*)((const float*)Ain + (size_t)grs * K);
  #pragma unroll
  for (int k0 = 0; k0 < K; k0 += 32) {
    half8 a = {};
    if (valid) {
      if (A32) {
        float4 f0 = arow32[(k0 >> 2) + quad * 2];
        float4 f1 = arow32[(k0 >> 2) + quad * 2 + 1];
        a = half8{(_Float16)f0.x, (_Float16)f0.y, (_Float16)f0.z, (_Float16)f0.w,
                  (_Float16)f1.x, (_Float16)f1.y, (_Float16)f1.z, (_Float16)f1.w};
      } else {
        a = arow[(k0 >> 3) + quad];
      }
    }
    half8 b0 = *(const half8*)&Wt[ 0 + m][k0 + quad * 8];
    half8 b1 = *(const half8*)&Wt[16 + m][k0 + quad * 8];
    half8 b2 = *(const half8*)&Wt[32 + m][k0 + quad * 8];
    half8 b3 = *(const half8*)&Wt[48 + m][k0 + quad * 8];
    acc0 = __builtin_amdgcn_mfma_f32_16x16x32_f16(a, b0, acc0, 0, 0, 0);
    acc1 = __builtin_amdgcn_mfma_f32_16x16x32_f16(a, b1, acc1, 0, 0, 0);
    acc2 = __builtin_amdgcn_mfma_f32_16x16x32_f16(a, b2, acc2, 0, 0, 0);
    acc3 = __builtin_amdgcn_mfma_f32_16x16x32_f16(a, b3, acc3, 0, 0, 0);
  }
  #pragma unroll
  for (int r = 0; r < 4; ++r) {
    int row = r0 + quad * 4 + r;
    if (row < N) {
      float dv = dinv[row];
      __half* dst = Y + (size_t)row * 64;
      dst[ 0 + m] = __float2half(acc0[r] * dv);
      dst[16 + m] = __float2half(acc1[r] * dv);
      dst[32 + m] = __float2half(acc2[r] * dv);
      dst[48 + m] = __float2half(acc3[r] * dv);
    }
  }
}

// ---------------- pass-major col-blocked gather body (shared by agg kernels)
// WAVE-UNIFORM control flow: loop bounds depend only on wave-uniform mm;
// `half` only selects the shfl INDEX; tail guard wraps the accumulate only,
// never a shfl. (R13's half-dependent bounds were divergent-shfl UB.)
#define GATHER_PASSES(acc, i0, N, Y2, col_s, row_bp, lane, half, ch2)          \
  _Pragma("unroll 1")                                                          \
  for (int b = 0; b < 7; ++b) {                                                \
    _Pragma("unroll")                                                          \
    for (int k = 0; k < NPW; ++k) {                                            \
      int i = (i0) + k;                                                        \
      if (i >= (N)) continue;                                                  \
      int p0 = row_bp[(size_t)i * NBLK + b];                                   \
      int p1 = row_bp[(size_t)i * NBLK + b + 1];                               \
      for (int bs = p0; bs < p1; bs += 64) {                                   \
        int mm = min(64, p1 - bs);                                             \
        int cv = (lane < mm) ? col_s[bs + lane] : 0;                           \
        int j = 0;                                                             \
        for (; j + 4 <= mm; j += 4) {                                          \
          int c0 = __shfl(cv, j + half);                                       \
          int c1 = __shfl(cv, j + 2 + half);                                   \
          float2 y0 = __half22float2(Y2[(size_t)c0 * 32 + ch2]);               \
          float2 y1 = __half22float2(Y2[(size_t)c1 * 32 + ch2]);               \
          acc[k].x += y0.x + y1.x; acc[k].y += y0.y + y1.y;                    \
        }                                                                      \
        for (; j < mm; j += 2) {                                               \
          int idx = j + half;                                                  \
          int cc = __shfl(cv, idx);                                            \
          if (idx < mm) {                                                      \
            float2 y = __half22float2(Y2[(size_t)cc * 32 + ch2]);              \
            acc[k].x += y.x; acc[k].y += y.y;                                  \
          }                                                                    \
        }                                                                      \
      }                                                                        \
    }                                                                          \
  }

// ---------------- aggregation, H=64: NPW nodes/wave, pass-major ------------
__global__ __launch_bounds__(256, 4) void agg64(const __half* __restrict__ Ys,
                                                const int* __restrict__ col_s,
                                                const int* __restrict__ row_bp,
                                                const float* __restrict__ dinv,
                                                const float* __restrict__ bias,
                                                __half* __restrict__ Xh, int N) {
  int wv = blockIdx.x * 4 + (threadIdx.x >> 6);
  int i0 = wv * NPW;
  if (i0 >= N) return;
  int lane = threadIdx.x & 63;
  int half = lane >> 5, ch2 = lane & 31;
  const __half2* Y2 = (const __half2*)Ys;
  float2 acc[NPW];
  #pragma unroll
  for (int k = 0; k < NPW; ++k) acc[k] = float2{0.f, 0.f};
  // self terms (half0 only; symmetrized by the final shfl_xor combine)
  if (half == 0) {
    #pragma unroll
    for (int k = 0; k < NPW; ++k) {
      int i = i0 + k;
      if (i < N) {
        float2 y = __half22float2(Y2[(size_t)i * 32 + ch2]);
        acc[k].x += y.x; acc[k].y += y.y;
      }
    }
  }
  GATHER_PASSES(acc, i0, N, Y2, col_s, row_bp, lane, half, ch2)
  #pragma unroll
  for (int k = 0; k < NPW; ++k) {
    acc[k].x += __shfl_xor(acc[k].x, 32);
    acc[k].y += __shfl_xor(acc[k].y, 32);
  }
  if (half == 0) {
    float2 b2 = ((const float2*)bias)[ch2];
    #pragma unroll
    for (int k = 0; k < NPW; ++k) {
      int i = i0 + k;
      if (i < N) {
        float di = dinv[i];
        ((__half2*)Xh)[(size_t)i * 32 + ch2] =
            __floats2half2_rn(fmaxf(di * acc[k].x + b2.x, 0.f),
                              fmaxf(di * acc[k].y + b2.y, 0.f));
      }
    }
  }
}

// ---------------- layer-4 aggregation fused with mean + W5 dot --------------
__global__ __launch_bounds__(256, 4) void agg64_final(const __half* __restrict__ Ys,
                                                      const int* __restrict__ col_s,
                                                      const int* __restrict__ row_bp,
                                                      const float* __restrict__ dinv,
                                                      const float* __restrict__ b4,
                                                      const float* __restrict__ W5,
                                                      float* __restrict__ h5,
                                                      float* __restrict__ red_m, int N) {
  int wave = threadIdx.x >> 6, lane = threadIdx.x & 63;
  int half = lane >> 5, ch2 = lane & 31;
  int wv = blockIdx.x * 4 + wave;
  int i0 = wv * NPW;
  const __half2* Y2 = (const __half2*)Ys;
  float2 w52 = ((const float2*)W5)[ch2];
  float2 b42 = ((const float2*)b4)[ch2];
  float2 msum = {0.f, 0.f};
  if (i0 < N) {
    float2 acc[NPW];
    #pragma unroll
    for (int k = 0; k < NPW; ++k) acc[k] = float2{0.f, 0.f};
    if (half == 0) {
      #pragma unroll
      for (int k = 0; k < NPW; ++k) {
        int i = i0 + k;
        if (i < N) {
          float2 y = __half22float2(Y2[(size_t)i * 32 + ch2]);
          acc[k].x += y.x; acc[k].y += y.y;
        }
      }
    }
    GATHER_PASSES(acc, i0, N, Y2, col_s, row_bp, lane, half, ch2)
    #pragma unroll
    for (int k = 0; k < NPW; ++k) {
      acc[k].x += __shfl_xor(acc[k].x, 32);
      acc[k].y += __shfl_xor(acc[k].y, 32);
    }
    #pragma unroll
    for (int k = 0; k < NPW; ++k) {
      int i = i0 + k;
      if (i < N) {
        float di = dinv[i];
        float hx = fmaxf(di * acc[k].x + b42.x, 0.f);
        float hy = fmaxf(di * acc[k].y + b42.y, 0.f);
        msum.x += hx;                    // duplicated across halves; half0 stores
        msum.y += hy;
        float p = waveSum(hx * w52.x + hy * w52.y);   // = 2 * dot (exact dup)
        if (lane == 0) h5[i] = di * p * 0.5f;
      }
    }
  }
  __shared__ float2 sh2[4][32];
  if (half == 0) sh2[wave][ch2] = msum;
  __syncthreads();
  if (threadIdx.x < 32) {
    int c = threadIdx.x;
    float tx = sh2[0][c].x + sh2[1][c].x + sh2[2][c].x + sh2[3][c].x;
    float ty = sh2[0][c].y + sh2[1][c].y + sh2[2][c].y + sh2[3][c].y;
    float* dst = &red_m[(blockIdx.x & 7) * 64];
    atomicAdd(&dst[2 * c], tx);
    atomicAdd(&dst[2 * c + 1], ty);
  }
}

// ---------------- scalar aggregation (layer 5): wave per node ---------------
__global__ __launch_bounds__(256) void agg_scalar(const float* __restrict__ h5,
                                                  const int* __restrict__ col_s,
                                                  const int* __restrict__ row_bp,
                                                  const float* __restrict__ dinv,
                                                  const float* __restrict__ b5,
                                                  float* __restrict__ out, int N) {
  int i = blockIdx.x * 4 + (threadIdx.x >> 6);
  if (i >= N) return;
  int lane = threadIdx.x & 63;
  int p0 = row_bp[(size_t)i * NBLK];
  int p1 = row_bp[(size_t)i * NBLK + 7];
  float acc = 0.f;
  for (int p = p0 + lane; p < p1; p += 64) acc += h5[col_s[p]];
  acc = waveSum(acc);
  if (lane == 0) out[i] = dinv[i] * (acc + h5[i]) + b5[0];
}

// ---------------- heads: v and prob_nothing ----------------
__global__ void heads(const float* __restrict__ red_m, const float* __restrict__ Wv,
                      const float* __restrict__ bv, const float* __restrict__ Wdn,
                      const float* __restrict__ bdn, float* __restrict__ out, int N) {
  int lane = threadIdx.x;   // 64 threads
  float s = 0.f;
  #pragma unroll
  for (int r = 0; r < 8; ++r) s += red_m[r * 64 + lane];
  float xm = s / (float)N;
  float pv = waveSum(xm * Wv[lane]);
  float pd = waveSum(xm * Wdn[lane]);
  if (lane == 0) {
    out[N] = pd + bdn[0];       // prob_nothing logit
    out[N + 1] = pv + bv[0];    // value head (final output slot)
  }
}

// ---------------- masked softmax: 1 full pass + combine + write -------------
__global__ void smax_pass1(const float* __restrict__ out, const int* __restrict__ ready,
                           float* __restrict__ bm, float* __restrict__ bs, int N) {
  int i = blockIdx.x * 256 + threadIdx.x;
  bool valid = false;
  float l = -3e38f;
  if (i < N) { if (ready[i]) { valid = true; l = out[i]; } }
  else if (i == N) { valid = true; l = out[N]; }
  float m = waveMax(l);
  __shared__ float shm[4], shs[4];
  int wv = threadIdx.x >> 6;
  if ((threadIdx.x & 63) == 0) shm[wv] = m;
  __syncthreads();
  float bmax = fmaxf(fmaxf(shm[0], shm[1]), fmaxf(shm[2], shm[3]));
  float e = valid ? expf(l - bmax) : 0.f;
  float s = waveSum(e);
  if ((threadIdx.x & 63) == 0) shs[wv] = s;
  __syncthreads();
  if (threadIdx.x == 0) {
    bm[blockIdx.x] = bmax;
    bs[blockIdx.x] = shs[0] + shs[1] + shs[2] + shs[3];
  }
}

__global__ void smax_comb(const float* __restrict__ bm, const float* __restrict__ bs,
                          float* __restrict__ red, int NB) {
  int t = threadIdx.x;
  float m = -3e38f;
  for (int b = t; b < NB; b += 256) m = fmaxf(m, bm[b]);
  m = waveMax(m);
  __shared__ float shm[4], shs[4];
  if ((t & 63) == 0) shm[t >> 6] = m;
  __syncthreads();
  float M = fmaxf(fmaxf(shm[0], shm[1]), fmaxf(shm[2], shm[3]));
  float s = 0.f;
  for (int b = t; b < NB; b += 256) s += bs[b] * expf(bm[b] - M);
  s = waveSum(s);
  if ((t & 63) == 0) shs[t >> 6] = s;
  __syncthreads();
  if (t == 0) { red[0] = M; red[1] = shs[0] + shs[1] + shs[2] + shs[3]; }
}

__global__ void smax_write(float* __restrict__ out, const int* __restrict__ ready,
                           const float* __restrict__ red, int N) {
  float M = red[0];
  float S = red[1];
  int i = blockIdx.x * blockDim.x + threadIdx.x;
  if (i < N) {
    out[i] = ready[i] ? (expf(out[i] - M) / S) : 0.f;
  } else if (i == N) {
    out[N] = expf(out[N] - M) / S;
  }
}

// ---------------------------------------------------------------------------
extern "C" void kernel_launch(void* const* d_in, const int* in_sizes, int n_in,
                              void* d_out, int out_size, void* d_ws, size_t ws_size,
                              hipStream_t stream) {
  const float* x    = (const float*)d_in[0];
  const int*   ei   = (const int*)d_in[1];
  const int*   ready= (const int*)d_in[2];
  const float* W1   = (const float*)d_in[3];
  const float* b1   = (const float*)d_in[4];
  const float* W2   = (const float*)d_in[5];
  const float* b2   = (const float*)d_in[6];
  const float* W3   = (const float*)d_in[7];
  const float* b3   = (const float*)d_in[8];
  const float* W4   = (const float*)d_in[9];
  const float* b4   = (const float*)d_in[10];
  const float* W5   = (const float*)d_in[11];
  const float* b5   = (const float*)d_in[12];
  const float* Wdn  = (const float*)d_in[13];
  const float* bdn  = (const float*)d_in[14];
  const float* Wv   = (const float*)d_in[15];
  const float* bv   = (const float*)d_in[16];
  float* out = (float*)d_out;

  int N = in_sizes[2];          // ready is (N,1)
  int E = in_sizes[1] / 2;      // edge_index is (2,E)
  int nbkt = (N + BROWS - 1) >> BSHIFT;   // 196 for N=100000

  // workspace carve (256B-aligned slices, byte-based)
  char* base = (char*)d_ws;
  size_t off = 0;
  auto allocB = [&](size_t bytes) -> void* {
    void* p = base + off;
    off += ((bytes + 255) / 256) * 256;
    return p;
  };
  size_t capBytes = (size_t)nbkt * CAP * 4;            // padded edge arrays
  float*    dinv       = (float*)allocB((size_t)N * 4);
  int*      row_bp     = (int*)allocB((size_t)N * NBLK * 4);
  int*      bucket_fill= (int*)allocB(256 * 4);
  int*      col_s      = (int*)allocB(capBytes);
  float*    h5         = (float*)allocB((size_t)N * 4);
  float*    red        = (float*)allocB(128 * 4);
  float*    red_m      = (float*)allocB(512 * 4);
  float*    bm         = (float*)allocB(512 * 4);
  float*    bs         = (float*)allocB(512 * 4);
  // Yb slot widened to hold eb (capBytes > N*64*2); eb dead before gemm1.
  size_t ybBytes = (size_t)N * 64 * 2;
  __half*   Yb         = (__half*)allocB(capBytes > ybBytes ? capBytes : ybBytes);
  __half*   Xh         = (__half*)allocB((size_t)N * 64 * 2);
  int*      eb         = (int*)Yb;
  (void)ws_size; (void)n_in; (void)out_size;

  int gN1 = (N + 1 + 255) / 256;
  int gW = (N + 3) / 4;                       // wave-per-node grids (agg_scalar)
  int nwaves = (N + NPW - 1) / NPW;           // 4000
  int gAgg = (nwaves + 3) / 4;                // 1000 blocks -> all resident
  int gA = (E + ACHUNK - 1) / ACHUNK;
  int gG = (N + 63) / 64;                     // mfma gemm grid

  hipMemsetAsync(red_m, 0, 512 * 4, stream);
  bucket_init<<<1, 256, 0, stream>>>(bucket_fill, nbkt);
  bin_edges<<<gA, 256, 0, stream>>>(ei, bucket_fill, eb, E);
  csr_bucket<<<nbkt, 256, 0, stream>>>(eb, bucket_fill, row_bp, dinv, col_s, N);

  // layer 1 (K = 128, fp32 A converted in-register)
  gemm_f16<128, true><<<gG, 256, 0, stream>>>(x, W1, dinv, Yb, N);
  agg64<<<gAgg, 256, 0, stream>>>(Yb, col_s, row_bp, dinv, b1, Xh, N);
  // layers 2-3 (K = 64, fp16 A)
  gemm_f16<64, false><<<gG, 256, 0, stream>>>(Xh, W2, dinv, Yb, N);
  agg64<<<gAgg, 256, 0, stream>>>(Yb, col_s, row_bp, dinv, b2, Xh, N);
  gemm_f16<64, false><<<gG, 256, 0, stream>>>(Xh, W3, dinv, Yb, N);
  agg64<<<gAgg, 256, 0, stream>>>(Yb, col_s, row_bp, dinv, b3, Xh, N);
  // layer 4 gemm + fused agg/mean/W5-dot
  gemm_f16<64, false><<<gG, 256, 0, stream>>>(Xh, W4, dinv, Yb, N);
  agg64_final<<<gAgg, 256, 0, stream>>>(Yb, col_s, row_bp, dinv, b4, W5,
                                        h5, red_m, N);

  // layer 5 + heads
  agg_scalar<<<gW, 256, 0, stream>>>(h5, col_s, row_bp, dinv, b5, out, N);
  heads<<<1, 64, 0, stream>>>(red_m, Wv, bv, Wdn, bdn, out, N);

  // masked softmax over out[0..N]
  smax_pass1<<<gN1, 256, 0, stream>>>(out, ready, bm, bs, N);
  smax_comb<<<1, 256, 0, stream>>>(bm, bs, red, gN1);
  smax_write<<<gN1, 256, 0, stream>>>(out, ready, red, N);
}

// Round 3
// 900.540 us; speedup vs baseline: 1.3624x; 1.3624x over previous
//
#include <hip/hip_runtime.h>
#include <hip/hip_bf16.h>
#include <hip/hip_fp16.h>

// ---------------------------------------------------------------------------
// GCN forward: 4x (gemm -> sym-norm aggregate -> +b -> relu), scalar 5th conv,
// mean-pool heads, masked softmax.
//
// R1..R12: see history (MFMA fp16 gemms, bucketed CSR, half2 lane-split
//     gather, fused layer-4 agg, single-pass softmax). 531 us.
// R13: col-blocked pass-synchronized gather. FAILED: divergent-shfl UB.
// R14: uniform-control-flow fix. PASSED but 251 us/agg (was 75): FETCH
//     dropped 157->107 MB (blocking works!) but acc[25] float2 = 50 VGPRs
//     of a 64-VGPR budget strangled MLP; 4000 waves couldn't hide the
//     col_s->shfl->Y2 chains. Latency-bound at 0.43 TB/s, VALUBusy 18.6%.
// R15: same blocking, execution fixed: (a) per-node accumulators in LDS
//     (wave-private slice, no barriers), register pressure ~40 -> loads
//     pipeline; (b) direct uniform col_s[j+half] loads (L1 broadcast)
//     replace masked-load+shfl chains; (c) NPW=13, grid 1924 blocks =
//     7693 waves (~30/CU co-resident, launch_bounds(256,8)); (d) col_s
//     tail padded so speculative read at p1 is always initialized.
// ---------------------------------------------------------------------------

#define WAVE 64
#define BSHIFT 9
#define BROWS 512           // rows per bucket
#define ACHUNK 8192         // edges per bin_edges block
#define CAP 17408           // bucket capacity (mean 16327, sigma ~128)
#define NBLK 8              // col-blocks (blocks 0..6 used for N=100000)
#define BLKSHIFT 14         // 16384 cols per block -> 2MB of Ys per block
#define NPW 13              // nodes per wave in agg kernels

using half8  = __attribute__((ext_vector_type(8))) _Float16;
using float4v = __attribute__((ext_vector_type(4))) float;

// ---------------- small helpers ----------------
__device__ __forceinline__ float waveSum(float v) {
  #pragma unroll
  for (int o = 32; o; o >>= 1) v += __shfl_xor(v, o);
  return v;
}
__device__ __forceinline__ float waveMax(float v) {
  #pragma unroll
  for (int o = 32; o; o >>= 1) v = fmaxf(v, __shfl_xor(v, o));
  return v;
}

// ---------------- bucket init: fixed-capacity bump-allocator seeds ----------
__global__ void bucket_init(int* __restrict__ bucket_fill, int nbkt) {
  int b = blockIdx.x * blockDim.x + threadIdx.x;
  if (b < nbkt) bucket_fill[b] = b * CAP;
}

// ---------------- bin edges into bucket-major packed array ----------------
// packed edge: (local_row 9b) << 17 | col (17b)   [N < 131072]
__global__ __launch_bounds__(256) void bin_edges(const int* __restrict__ ei,
                                                 int* __restrict__ bucket_fill,
                                                 int* __restrict__ eb, int E) {
  __shared__ int hist[256], basee[256], rank[256];
  int t = threadIdx.x;
  hist[t] = 0; rank[t] = 0;
  __syncthreads();
  int c0 = blockIdx.x * ACHUNK;
  #pragma unroll
  for (int k = 0; k < ACHUNK / 256; ++k) {
    int e = c0 + k * 256 + t;
    if (e < E) atomicAdd(&hist[ei[e] >> BSHIFT], 1);
  }
  __syncthreads();
  if (hist[t]) basee[t] = atomicAdd(&bucket_fill[t], hist[t]);
  __syncthreads();
  #pragma unroll
  for (int k = 0; k < ACHUNK / 256; ++k) {
    int e = c0 + k * 256 + t;
    if (e < E) {
      int r = ei[e], c = ei[E + e];
      int bb = r >> BSHIFT;
      int p = basee[bb] + atomicAdd(&rank[bb], 1);
      eb[p] = ((r & (BROWS - 1)) << 17) | c;
    }
  }
}

// ---------------- per-bucket CSR finalize: (row, col-block) two-level sort --
// E0 = b*CAP; E1 = bucket_fill[b]. Output: col_s grouped by row then by
// col-block; row_bp[i*8+q] = start of (row i, block q); row end = bp[i*8+7]
// (block 7 is always empty since col < 114688).
__global__ __launch_bounds__(256) void csr_bucket(const int* __restrict__ eb,
                                                  const int* __restrict__ bucket_fill,
                                                  int* __restrict__ row_bp,
                                                  float* __restrict__ dinv,
                                                  int* __restrict__ col_s, int N) {
  __shared__ int deg[BROWS * NBLK];   // 4096: counts, then exclusive prefix
  __shared__ int fill[BROWS * NBLK];
  __shared__ int sh[256];
  int b = blockIdx.x;
  int base = b << BSHIFT;
  int R = min(BROWS, N - base);
  int t = threadIdx.x;
  for (int q = t; q < BROWS * NBLK; q += 256) { deg[q] = 0; fill[q] = 0; }
  __syncthreads();
  int E0 = b * CAP, E1 = bucket_fill[b];
  int tot = E1 - E0;
  // pad one slot past the bucket's edges so agg's speculative col_s[p1]
  // read is always initialized (guarded accumulate ignores its value).
  if (t == 0 && tot < CAP) col_s[E1] = 0;
  for (int e = E0 + t; e < E1; e += 256) {
    int v = eb[e];
    atomicAdd(&deg[(v >> 17) * NBLK + ((v & 0x1FFFF) >> BLKSHIFT)], 1);
  }
  __syncthreads();
  // exclusive prefix over 4096 cells (row-major: row, block). t owns 16 cells.
  int loc[16];
  int s = 0;
  #pragma unroll
  for (int q = 0; q < 16; ++q) { loc[q] = s; s += deg[t * 16 + q]; }
  sh[t] = s;
  __syncthreads();
  for (int o = 1; o < 256; o <<= 1) {
    int x = (t >= o) ? sh[t - o] : 0;
    __syncthreads();
    sh[t] += x;
    __syncthreads();
  }
  int ex = sh[t] - s;
  #pragma unroll
  for (int q = 0; q < 16; ++q) deg[t * 16 + q] = ex + loc[q];   // -> prefix
  __syncthreads();
  for (int i = t; i < R; i += 256) {
    int st = deg[i * NBLK];
    int en = (i == BROWS - 1) ? tot : deg[(i + 1) * NBLK];
    dinv[base + i] = rsqrtf((float)(en - st + 1));    // +1 self-loop
    #pragma unroll
    for (int q = 0; q < NBLK; ++q)
      row_bp[(size_t)(base + i) * NBLK + q] = E0 + deg[i * NBLK + q];
  }
  for (int e = E0 + t; e < E1; e += 256) {
    int v = eb[e];
    int c = v & 0x1FFFF;
    int cell = (v >> 17) * NBLK + (c >> BLKSHIFT);
    int p = E0 + deg[cell] + atomicAdd(&fill[cell], 1);
    col_s[p] = c;
  }
}

// ---------------- MFMA GEMM: Y[N][64] = fp16(dinv (.) (A[N][K] @ W[K][64]))
template <int K, bool A32>
__global__ __launch_bounds__(256) void gemm_f16(const void* __restrict__ Ain,
                                                const float* __restrict__ Wg,
                                                const float* __restrict__ dinv,
                                                __half* __restrict__ Y, int N) {
  __shared__ _Float16 Wt[64][K + 8];
  int t = threadIdx.x;
  for (int idx = t; idx < K * 64; idx += 256) {
    int k = idx >> 6, n = idx & 63;
    Wt[n][k] = (_Float16)Wg[idx];
  }
  __syncthreads();
  int wave = t >> 6, lane = t & 63;
  int m = lane & 15, quad = lane >> 4;
  int r0 = blockIdx.x * 64 + wave * 16;
  float4v acc0 = {0.f, 0.f, 0.f, 0.f}, acc1 = {0.f, 0.f, 0.f, 0.f};
  float4v acc2 = {0.f, 0.f, 0.f, 0.f}, acc3 = {0.f, 0.f, 0.f, 0.f};
  int gr = r0 + m;
  bool valid = gr < N;
  int grs = valid ? gr : 0;
  const half8* arow = (const half8*)((const _Float16*)Ain + (size_t)grs * K);
  const float4* arow32 = (const float4*)((const float*)Ain + (size_t)grs * K);
  #pragma unroll
  for (int k0 = 0; k0 < K; k0 += 32) {
    half8 a = {};
    if (valid) {
      if (A32) {
        float4 f0 = arow32[(k0 >> 2) + quad * 2];
        float4 f1 = arow32[(k0 >> 2) + quad * 2 + 1];
        a = half8{(_Float16)f0.x, (_Float16)f0.y, (_Float16)f0.z, (_Float16)f0.w,
                  (_Float16)f1.x, (_Float16)f1.y, (_Float16)f1.z, (_Float16)f1.w};
      } else {
        a = arow[(k0 >> 3) + quad];
      }
    }
    half8 b0 = *(const half8*)&Wt[ 0 + m][k0 + quad * 8];
    half8 b1 = *(const half8*)&Wt[16 + m][k0 + quad * 8];
    half8 b2 = *(const half8*)&Wt[32 + m][k0 + quad * 8];
    half8 b3 = *(const half8*)&Wt[48 + m][k0 + quad * 8];
    acc0 = __builtin_amdgcn_mfma_f32_16x16x32_f16(a, b0, acc0, 0, 0, 0);
    acc1 = __builtin_amdgcn_mfma_f32_16x16x32_f16(a, b1, acc1, 0, 0, 0);
    acc2 = __builtin_amdgcn_mfma_f32_16x16x32_f16(a, b2, acc2, 0, 0, 0);
    acc3 = __builtin_amdgcn_mfma_f32_16x16x32_f16(a, b3, acc3, 0, 0, 0);
  }
  #pragma unroll
  for (int r = 0; r < 4; ++r) {
    int row = r0 + quad * 4 + r;
    if (row < N) {
      float dv = dinv[row];
      __half* dst = Y + (size_t)row * 64;
      dst[ 0 + m] = __float2half(acc0[r] * dv);
      dst[16 + m] = __float2half(acc1[r] * dv);
      dst[32 + m] = __float2half(acc2[r] * dv);
      dst[48 + m] = __float2half(acc3[r] * dv);
    }
  }
}

// ---------------- pass-major col-blocked gather core ------------------------
// Per wave: NPW nodes, LDS accumulator slice lacc[NPW][32] (float2/ch2-pair).
// All control flow wave-uniform; the two 32-lane halves take alternating
// edges via the uniform address col_s[j + half]; guard wraps accumulate only.
// Speculative col_s[p1] read is initialized (csr_bucket pad).
__device__ __forceinline__ void gather_blocks(const __half2* __restrict__ Y2,
                                              const int* __restrict__ col_s,
                                              const int* __restrict__ row_bp,
                                              float2 (*lacc)[32],
                                              int i0, int N,
                                              int half, int ch2) {
  #pragma unroll 1
  for (int b = 0; b < 7; ++b) {
    #pragma unroll 1
    for (int k = 0; k < NPW; ++k) {
      int i = i0 + k;
      if (i >= N) break;                           // wave-uniform
      int p0 = row_bp[(size_t)i * NBLK + b];
      int p1 = row_bp[(size_t)i * NBLK + b + 1];
      float2 s = {0.f, 0.f};
      int j = p0;
      for (; j + 4 <= p1; j += 4) {                // 4 edges, all valid
        int c0 = col_s[j + half];
        int c1 = col_s[j + 2 + half];
        float2 y0 = __half22float2(Y2[(size_t)c0 * 32 + ch2]);
        float2 y1 = __half22float2(Y2[(size_t)c1 * 32 + ch2]);
        s.x += y0.x + y1.x; s.y += y0.y + y1.y;
      }
      for (; j < p1; j += 2) {                     // 1-3 edges remain
        int cc = col_s[j + half];                  // <= p1: padded/valid
        float2 y = __half22float2(Y2[(size_t)cc * 32 + ch2]);
        if (j + half < p1) { s.x += y.x; s.y += y.y; }
      }
      s.x += __shfl_xor(s.x, 32);                  // combine halves
      s.y += __shfl_xor(s.y, 32);
      if (half == 0) {
        lacc[k][ch2].x += s.x;
        lacc[k][ch2].y += s.y;
      }
    }
  }
}

// ---------------- aggregation, H=64: NPW nodes/wave, pass-major ------------
__global__ __launch_bounds__(256, 8) void agg64(const __half* __restrict__ Ys,
                                                const int* __restrict__ col_s,
                                                const int* __restrict__ row_bp,
                                                const float* __restrict__ dinv,
                                                const float* __restrict__ bias,
                                                __half* __restrict__ Xh, int N) {
  __shared__ float2 lacc[4][NPW][32];
  int w = threadIdx.x >> 6;
  int wv = blockIdx.x * 4 + w;
  int i0 = wv * NPW;
  if (i0 >= N) return;
  int lane = threadIdx.x & 63;
  int half = lane >> 5, ch2 = lane & 31;
  const __half2* Y2 = (const __half2*)Ys;
  if (half == 0) {
    #pragma unroll
    for (int k = 0; k < NPW; ++k) lacc[w][k][ch2] = float2{0.f, 0.f};
  }
  gather_blocks(Y2, col_s, row_bp, lacc[w], i0, N, half, ch2);
  if (half == 0) {
    float2 b2 = ((const float2*)bias)[ch2];
    #pragma unroll 1
    for (int k = 0; k < NPW; ++k) {
      int i = i0 + k;
      if (i >= N) break;
      float2 s = lacc[w][k][ch2];
      float2 sy = __half22float2(Y2[(size_t)i * 32 + ch2]);   // self term
      float di = dinv[i];
      ((__half2*)Xh)[(size_t)i * 32 + ch2] =
          __floats2half2_rn(fmaxf(di * (s.x + sy.x) + b2.x, 0.f),
                            fmaxf(di * (s.y + sy.y) + b2.y, 0.f));
    }
  }
}

// ---------------- layer-4 aggregation fused with mean + W5 dot --------------
__global__ __launch_bounds__(256, 8) void agg64_final(const __half* __restrict__ Ys,
                                                      const int* __restrict__ col_s,
                                                      const int* __restrict__ row_bp,
                                                      const float* __restrict__ dinv,
                                                      const float* __restrict__ b4,
                                                      const float* __restrict__ W5,
                                                      float* __restrict__ h5,
                                                      float* __restrict__ red_m, int N) {
  __shared__ float2 lacc[4][NPW][32];
  __shared__ float2 sh2[4][32];
  int w = threadIdx.x >> 6, lane = threadIdx.x & 63;
  int half = lane >> 5, ch2 = lane & 31;
  int wv = blockIdx.x * 4 + w;
  int i0 = wv * NPW;
  const __half2* Y2 = (const __half2*)Ys;
  float2 w52 = ((const float2*)W5)[ch2];
  float2 b42 = ((const float2*)b4)[ch2];
  float2 msum = {0.f, 0.f};
  if (i0 < N) {
    if (half == 0) {
      #pragma unroll
      for (int k = 0; k < NPW; ++k) lacc[w][k][ch2] = float2{0.f, 0.f};
    }
    gather_blocks(Y2, col_s, row_bp, lacc[w], i0, N, half, ch2);
    #pragma unroll 1
    for (int k = 0; k < NPW; ++k) {
      int i = i0 + k;
      if (i >= N) break;
      float2 s = lacc[w][k][ch2];              // both halves read (identical)
      float2 sy = __half22float2(Y2[(size_t)i * 32 + ch2]);
      float di = dinv[i];
      float hx = fmaxf(di * (s.x + sy.x) + b42.x, 0.f);
      float hy = fmaxf(di * (s.y + sy.y) + b42.y, 0.f);
      msum.x += hx;                    // duplicated across halves; half0 stores
      msum.y += hy;
      float p = waveSum(hx * w52.x + hy * w52.y);   // = 2 * dot (exact dup)
      if (lane == 0) h5[i] = di * p * 0.5f;
    }
  }
  if (half == 0) sh2[w][ch2] = msum;
  __syncthreads();
  if (threadIdx.x < 32) {
    int c = threadIdx.x;
    float tx = sh2[0][c].x + sh2[1][c].x + sh2[2][c].x + sh2[3][c].x;
    float ty = sh2[0][c].y + sh2[1][c].y + sh2[2][c].y + sh2[3][c].y;
    float* dst = &red_m[(blockIdx.x & 7) * 64];
    atomicAdd(&dst[2 * c], tx);
    atomicAdd(&dst[2 * c + 1], ty);
  }
}

// ---------------- scalar aggregation (layer 5): wave per node ---------------
__global__ __launch_bounds__(256) void agg_scalar(const float* __restrict__ h5,
                                                  const int* __restrict__ col_s,
                                                  const int* __restrict__ row_bp,
                                                  const float* __restrict__ dinv,
                                                  const float* __restrict__ b5,
                                                  float* __restrict__ out, int N) {
  int i = blockIdx.x * 4 + (threadIdx.x >> 6);
  if (i >= N) return;
  int lane = threadIdx.x & 63;
  int p0 = row_bp[(size_t)i * NBLK];
  int p1 = row_bp[(size_t)i * NBLK + 7];
  float acc = 0.f;
  for (int p = p0 + lane; p < p1; p += 64) acc += h5[col_s[p]];
  acc = waveSum(acc);
  if (lane == 0) out[i] = dinv[i] * (acc + h5[i]) + b5[0];
}

// ---------------- heads: v and prob_nothing ----------------
__global__ void heads(const float* __restrict__ red_m, const float* __restrict__ Wv,
                      const float* __restrict__ bv, const float* __restrict__ Wdn,
                      const float* __restrict__ bdn, float* __restrict__ out, int N) {
  int lane = threadIdx.x;   // 64 threads
  float s = 0.f;
  #pragma unroll
  for (int r = 0; r < 8; ++r) s += red_m[r * 64 + lane];
  float xm = s / (float)N;
  float pv = waveSum(xm * Wv[lane]);
  float pd = waveSum(xm * Wdn[lane]);
  if (lane == 0) {
    out[N] = pd + bdn[0];       // prob_nothing logit
    out[N + 1] = pv + bv[0];    // value head (final output slot)
  }
}

// ---------------- masked softmax: 1 full pass + combine + write -------------
__global__ void smax_pass1(const float* __restrict__ out, const int* __restrict__ ready,
                           float* __restrict__ bm, float* __restrict__ bs, int N) {
  int i = blockIdx.x * 256 + threadIdx.x;
  bool valid = false;
  float l = -3e38f;
  if (i < N) { if (ready[i]) { valid = true; l = out[i]; } }
  else if (i == N) { valid = true; l = out[N]; }
  float m = waveMax(l);
  __shared__ float shm[4], shs[4];
  int wv = threadIdx.x >> 6;
  if ((threadIdx.x & 63) == 0) shm[wv] = m;
  __syncthreads();
  float bmax = fmaxf(fmaxf(shm[0], shm[1]), fmaxf(shm[2], shm[3]));
  float e = valid ? expf(l - bmax) : 0.f;
  float s = waveSum(e);
  if ((threadIdx.x & 63) == 0) shs[wv] = s;
  __syncthreads();
  if (threadIdx.x == 0) {
    bm[blockIdx.x] = bmax;
    bs[blockIdx.x] = shs[0] + shs[1] + shs[2] + shs[3];
  }
}

__global__ void smax_comb(const float* __restrict__ bm, const float* __restrict__ bs,
                          float* __restrict__ red, int NB) {
  int t = threadIdx.x;
  float m = -3e38f;
  for (int b = t; b < NB; b += 256) m = fmaxf(m, bm[b]);
  m = waveMax(m);
  __shared__ float shm[4], shs[4];
  if ((t & 63) == 0) shm[t >> 6] = m;
  __syncthreads();
  float M = fmaxf(fmaxf(shm[0], shm[1]), fmaxf(shm[2], shm[3]));
  float s = 0.f;
  for (int b = t; b < NB; b += 256) s += bs[b] * expf(bm[b] - M);
  s = waveSum(s);
  if ((t & 63) == 0) shs[t >> 6] = s;
  __syncthreads();
  if (t == 0) { red[0] = M; red[1] = shs[0] + shs[1] + shs[2] + shs[3]; }
}

__global__ void smax_write(float* __restrict__ out, const int* __restrict__ ready,
                           const float* __restrict__ red, int N) {
  float M = red[0];
  float S = red[1];
  int i = blockIdx.x * blockDim.x + threadIdx.x;
  if (i < N) {
    out[i] = ready[i] ? (expf(out[i] - M) / S) : 0.f;
  } else if (i == N) {
    out[N] = expf(out[N] - M) / S;
  }
}

// ---------------------------------------------------------------------------
extern "C" void kernel_launch(void* const* d_in, const int* in_sizes, int n_in,
                              void* d_out, int out_size, void* d_ws, size_t ws_size,
                              hipStream_t stream) {
  const float* x    = (const float*)d_in[0];
  const int*   ei   = (const int*)d_in[1];
  const int*   ready= (const int*)d_in[2];
  const float* W1   = (const float*)d_in[3];
  const float* b1   = (const float*)d_in[4];
  const float* W2   = (const float*)d_in[5];
  const float* b2   = (const float*)d_in[6];
  const float* W3   = (const float*)d_in[7];
  const float* b3   = (const float*)d_in[8];
  const float* W4   = (const float*)d_in[9];
  const float* b4   = (const float*)d_in[10];
  const float* W5   = (const float*)d_in[11];
  const float* b5   = (const float*)d_in[12];
  const float* Wdn  = (const float*)d_in[13];
  const float* bdn  = (const float*)d_in[14];
  const float* Wv   = (const float*)d_in[15];
  const float* bv   = (const float*)d_in[16];
  float* out = (float*)d_out;

  int N = in_sizes[2];          // ready is (N,1)
  int E = in_sizes[1] / 2;      // edge_index is (2,E)
  int nbkt = (N + BROWS - 1) >> BSHIFT;   // 196 for N=100000

  // workspace carve (256B-aligned slices, byte-based)
  char* base = (char*)d_ws;
  size_t off = 0;
  auto allocB = [&](size_t bytes) -> void* {
    void* p = base + off;
    off += ((bytes + 255) / 256) * 256;
    return p;
  };
  size_t capBytes = (size_t)nbkt * CAP * 4;            // padded edge arrays
  float*    dinv       = (float*)allocB((size_t)N * 4);
  int*      row_bp     = (int*)allocB((size_t)N * NBLK * 4);
  int*      bucket_fill= (int*)allocB(256 * 4);
  int*      col_s      = (int*)allocB(capBytes + 256);
  float*    h5         = (float*)allocB((size_t)N * 4);
  float*    red        = (float*)allocB(128 * 4);
  float*    red_m      = (float*)allocB(512 * 4);
  float*    bm         = (float*)allocB(512 * 4);
  float*    bs         = (float*)allocB(512 * 4);
  // Yb slot widened to hold eb (capBytes > N*64*2); eb dead before gemm1.
  size_t ybBytes = (size_t)N * 64 * 2;
  __half*   Yb         = (__half*)allocB(capBytes > ybBytes ? capBytes : ybBytes);
  __half*   Xh         = (__half*)allocB((size_t)N * 64 * 2);
  int*      eb         = (int*)Yb;
  (void)ws_size; (void)n_in; (void)out_size;

  int gN1 = (N + 1 + 255) / 256;
  int gW = (N + 3) / 4;                       // wave-per-node grids (agg_scalar)
  int nwaves = (N + NPW - 1) / NPW;           // 7693
  int gAgg = (nwaves + 3) / 4;                // 1924 blocks -> ~all resident
  int gA = (E + ACHUNK - 1) / ACHUNK;
  int gG = (N + 63) / 64;                     // mfma gemm grid

  hipMemsetAsync(red_m, 0, 512 * 4, stream);
  bucket_init<<<1, 256, 0, stream>>>(bucket_fill, nbkt);
  bin_edges<<<gA, 256, 0, stream>>>(ei, bucket_fill, eb, E);
  csr_bucket<<<nbkt, 256, 0, stream>>>(eb, bucket_fill, row_bp, dinv, col_s, N);

  // layer 1 (K = 128, fp32 A converted in-register)
  gemm_f16<128, true><<<gG, 256, 0, stream>>>(x, W1, dinv, Yb, N);
  agg64<<<gAgg, 256, 0, stream>>>(Yb, col_s, row_bp, dinv, b1, Xh, N);
  // layers 2-3 (K = 64, fp16 A)
  gemm_f16<64, false><<<gG, 256, 0, stream>>>(Xh, W2, dinv, Yb, N);
  agg64<<<gAgg, 256, 0, stream>>>(Yb, col_s, row_bp, dinv, b2, Xh, N);
  gemm_f16<64, false><<<gG, 256, 0, stream>>>(Xh, W3, dinv, Yb, N);
  agg64<<<gAgg, 256, 0, stream>>>(Yb, col_s, row_bp, dinv, b3, Xh, N);
  // layer 4 gemm + fused agg/mean/W5-dot
  gemm_f16<64, false><<<gG, 256, 0, stream>>>(Xh, W4, dinv, Yb, N);
  agg64_final<<<gAgg, 256, 0, stream>>>(Yb, col_s, row_bp, dinv, b4, W5,
                                        h5, red_m, N);

  // layer 5 + heads
  agg_scalar<<<gW, 256, 0, stream>>>(h5, col_s, row_bp, dinv, b5, out, N);
  heads<<<1, 64, 0, stream>>>(red_m, Wv, bv, Wdn, bdn, out, N);

  // masked softmax over out[0..N]
  smax_pass1<<<gN1, 256, 0, stream>>>(out, ready, bm, bs, N);
  smax_comb<<<1, 256, 0, stream>>>(bm, bs, red, gN1);
  smax_write<<<gN1, 256, 0, stream>>>(out, ready, red, N);
}

// Round 4
// 717.430 us; speedup vs baseline: 1.7101x; 1.2552x over previous
//
#include <hip/hip_runtime.h>
#include <hip/hip_bf16.h>
#include <hip/hip_fp16.h>

// ---------------------------------------------------------------------------
// GCN forward: 4x (gemm -> sym-norm aggregate -> +b -> relu), scalar 5th conv,
// mean-pool heads, masked softmax.
//
// R1..R12: see history (MFMA fp16 gemms, bucketed CSR, half2 lane-split
//     gather, fused layer-4 agg, single-pass softmax). 531 us.
// R13: col-blocked pass-synchronized gather. FAILED: divergent-shfl UB.
// R14: fixed; FETCH 157->107MB (blocking works) but acc[25] = 50/64 VGPRs,
//     latency-bound, 251 us/agg.
// R15: LDS accumulators + NPW=13. 162 us/agg, VALUBusy 40%, VGPR 20:
//     per-(node,block) segments of ~4.6 edges processed node-serially ->
//     dependent chains, no ILP. Fragmentation is the enemy.
// R16: block-MAJOR edge layout. Within each 512-row bucket, edges sorted by
//     (col-block, row); entries keep the packed (local_row<<17|col) form.
//     A wave owns 8 rows -> per block ONE contiguous ~37-edge range, streamed
//     edge-flat (half-wave per edge, uniform colp[j+half] broadcast, 128B
//     Y-row per edge), accumulating into PER-HALF private LDS copies
//     lacc[w][half][8][32] (no races by construction, no shfl, no branches).
//     2x unroll -> 2 Y2 loads in flight. 16KB LDS/WG, 8 WG/CU. agg_scalar
//     rewritten on flat ranges with lane-per-edge + LDS atomics.
// ---------------------------------------------------------------------------

#define WAVE 64
#define BSHIFT 9
#define BROWS 512           // rows per bucket
#define ACHUNK 8192         // edges per bin_edges block
#define CAP 17408           // bucket capacity (mean 16327, sigma ~128)
#define NBLK 8              // col-blocks (cells); blocks 0..6 used for N=100000
#define BLKSHIFT 14         // 16384 cols per block -> 2MB of Ys per block
#define NPW 8               // rows per wave (divides 512 and the tail bucket)

using half8  = __attribute__((ext_vector_type(8))) _Float16;
using float4v = __attribute__((ext_vector_type(4))) float;

// ---------------- small helpers ----------------
__device__ __forceinline__ float waveSum(float v) {
  #pragma unroll
  for (int o = 32; o; o >>= 1) v += __shfl_xor(v, o);
  return v;
}
__device__ __forceinline__ float waveMax(float v) {
  #pragma unroll
  for (int o = 32; o; o >>= 1) v = fmaxf(v, __shfl_xor(v, o));
  return v;
}

// ---------------- bucket init: fixed-capacity bump-allocator seeds ----------
__global__ void bucket_init(int* __restrict__ bucket_fill, int nbkt) {
  int b = blockIdx.x * blockDim.x + threadIdx.x;
  if (b < nbkt) bucket_fill[b] = b * CAP;
}

// ---------------- bin edges into bucket-major packed array ----------------
// packed edge: (local_row 9b) << 17 | col (17b)   [N < 131072]
__global__ __launch_bounds__(256) void bin_edges(const int* __restrict__ ei,
                                                 int* __restrict__ bucket_fill,
                                                 int* __restrict__ eb, int E) {
  __shared__ int hist[256], basee[256], rank[256];
  int t = threadIdx.x;
  hist[t] = 0; rank[t] = 0;
  __syncthreads();
  int c0 = blockIdx.x * ACHUNK;
  #pragma unroll
  for (int k = 0; k < ACHUNK / 256; ++k) {
    int e = c0 + k * 256 + t;
    if (e < E) atomicAdd(&hist[ei[e] >> BSHIFT], 1);
  }
  __syncthreads();
  if (hist[t]) basee[t] = atomicAdd(&bucket_fill[t], hist[t]);
  __syncthreads();
  #pragma unroll
  for (int k = 0; k < ACHUNK / 256; ++k) {
    int e = c0 + k * 256 + t;
    if (e < E) {
      int r = ei[e], c = ei[E + e];
      int bb = r >> BSHIFT;
      int p = basee[bb] + atomicAdd(&rank[bb], 1);
      eb[p] = ((r & (BROWS - 1)) << 17) | c;
    }
  }
}

// ---------------- per-bucket CSR finalize: (col-block, row) sort ------------
// E0 = b*CAP; E1 = bucket_fill[b]. Output: colp entries (packed row|col)
// sorted by cell = blk*512 + row (b-major). gseg[bucket*4096 + cell] = global
// start of cell; contiguity makes [gseg[cell], gseg[cell+k]) valid ranges.
// Block 7 is empty (col < 114688) so its prefix entries equal E1 (sentinels).
__global__ __launch_bounds__(256) void csr_bucket(const int* __restrict__ eb,
                                                  const int* __restrict__ bucket_fill,
                                                  int* __restrict__ gseg,
                                                  float* __restrict__ dinv,
                                                  int* __restrict__ colp, int N) {
  __shared__ int deg[BROWS * NBLK];   // b-major cells: counts, then prefix
  __shared__ int fill[BROWS * NBLK];
  __shared__ int sh[256];
  int b = blockIdx.x;
  int base = b << BSHIFT;
  int R = min(BROWS, N - base);
  int t = threadIdx.x;
  for (int q = t; q < BROWS * NBLK; q += 256) { deg[q] = 0; fill[q] = 0; }
  __syncthreads();
  int E0 = b * CAP, E1 = bucket_fill[b];
  for (int e = E0 + t; e < E1; e += 256) {
    int v = eb[e];
    atomicAdd(&deg[((v & 0x1FFFF) >> BLKSHIFT) * BROWS + (v >> 17)], 1);
  }
  __syncthreads();
  // exclusive prefix over 4096 cells (linear in b-major order). t owns 16.
  int loc[16];
  int s = 0;
  #pragma unroll
  for (int q = 0; q < 16; ++q) { loc[q] = s; s += deg[t * 16 + q]; }
  sh[t] = s;
  __syncthreads();
  for (int o = 1; o < 256; o <<= 1) {
    int x = (t >= o) ? sh[t - o] : 0;
    __syncthreads();
    sh[t] += x;
    __syncthreads();
  }
  int ex = sh[t] - s;
  #pragma unroll
  for (int q = 0; q < 16; ++q) deg[t * 16 + q] = ex + loc[q];   // -> prefix
  __syncthreads();
  for (int q = t; q < BROWS * NBLK; q += 256)
    gseg[(size_t)b * (BROWS * NBLK) + q] = E0 + deg[q];
  for (int e = E0 + t; e < E1; e += 256) {
    int v = eb[e];
    int cell = ((v & 0x1FFFF) >> BLKSHIFT) * BROWS + (v >> 17);
    int p = E0 + deg[cell] + atomicAdd(&fill[cell], 1);
    colp[p] = v;                       // keep packed (row|col)
  }
  __syncthreads();
  // row degree = sum of its cells' fills
  for (int i = t; i < R; i += 256) {
    int d = 0;
    #pragma unroll
    for (int q = 0; q < NBLK; ++q) d += fill[q * BROWS + i];
    dinv[base + i] = rsqrtf((float)(d + 1));    // +1 self-loop
  }
}

// ---------------- MFMA GEMM: Y[N][64] = fp16(dinv (.) (A[N][K] @ W[K][64]))
template <int K, bool A32>
__global__ __launch_bounds__(256) void gemm_f16(const void* __restrict__ Ain,
                                                const float* __restrict__ Wg,
                                                const float* __restrict__ dinv,
                                                __half* __restrict__ Y, int N) {
  __shared__ _Float16 Wt[64][K + 8];
  int t = threadIdx.x;
  for (int idx = t; idx < K * 64; idx += 256) {
    int k = idx >> 6, n = idx & 63;
    Wt[n][k] = (_Float16)Wg[idx];
  }
  __syncthreads();
  int wave = t >> 6, lane = t & 63;
  int m = lane & 15, quad = lane >> 4;
  int r0 = blockIdx.x * 64 + wave * 16;
  float4v acc0 = {0.f, 0.f, 0.f, 0.f}, acc1 = {0.f, 0.f, 0.f, 0.f};
  float4v acc2 = {0.f, 0.f, 0.f, 0.f}, acc3 = {0.f, 0.f, 0.f, 0.f};
  int gr = r0 + m;
  bool valid = gr < N;
  int grs = valid ? gr : 0;
  const half8* arow = (const half8*)((const _Float16*)Ain + (size_t)grs * K);
  const float4* arow32 = (const float4*)((const float*)Ain + (size_t)grs * K);
  #pragma unroll
  for (int k0 = 0; k0 < K; k0 += 32) {
    half8 a = {};
    if (valid) {
      if (A32) {
        float4 f0 = arow32[(k0 >> 2) + quad * 2];
        float4 f1 = arow32[(k0 >> 2) + quad * 2 + 1];
        a = half8{(_Float16)f0.x, (_Float16)f0.y, (_Float16)f0.z, (_Float16)f0.w,
                  (_Float16)f1.x, (_Float16)f1.y, (_Float16)f1.z, (_Float16)f1.w};
      } else {
        a = arow[(k0 >> 3) + quad];
      }
    }
    half8 b0 = *(const half8*)&Wt[ 0 + m][k0 + quad * 8];
    half8 b1 = *(const half8*)&Wt[16 + m][k0 + quad * 8];
    half8 b2 = *(const half8*)&Wt[32 + m][k0 + quad * 8];
    half8 b3 = *(const half8*)&Wt[48 + m][k0 + quad * 8];
    acc0 = __builtin_amdgcn_mfma_f32_16x16x32_f16(a, b0, acc0, 0, 0, 0);
    acc1 = __builtin_amdgcn_mfma_f32_16x16x32_f16(a, b1, acc1, 0, 0, 0);
    acc2 = __builtin_amdgcn_mfma_f32_16x16x32_f16(a, b2, acc2, 0, 0, 0);
    acc3 = __builtin_amdgcn_mfma_f32_16x16x32_f16(a, b3, acc3, 0, 0, 0);
  }
  #pragma unroll
  for (int r = 0; r < 4; ++r) {
    int row = r0 + quad * 4 + r;
    if (row < N) {
      float dv = dinv[row];
      __half* dst = Y + (size_t)row * 64;
      dst[ 0 + m] = __float2half(acc0[r] * dv);
      dst[16 + m] = __float2half(acc1[r] * dv);
      dst[32 + m] = __float2half(acc2[r] * dv);
      dst[48 + m] = __float2half(acc3[r] * dv);
    }
  }
}

// ---------------- flat-range gather body (shared by agg64 / agg64_final) ----
// Wave owns 8 rows of one bucket; for block b its edges are ONE contiguous
// range [q0,q1), row-sorted. Halves take alternating edges (uniform broadcast
// colp loads); each half accumulates into its OWN LDS copy -> no races, no
// shfl, no branches. lacc layout: [half][8 rows][32 ch2] float2.
__device__ __forceinline__ void gather_flat(const __half2* __restrict__ Y2,
                                            const int* __restrict__ colp,
                                            const int* __restrict__ gs,
                                            float2 (*lh)[32],   // this half's copy
                                            int r0, int half, int ch2, int nbu) {
  #pragma unroll 1
  for (int b = 0; b < nbu; ++b) {
    int q0 = gs[b * BROWS + r0];
    int q1 = gs[b * BROWS + r0 + NPW];
    int j = q0;
    for (; j + 4 <= q1; j += 4) {            // 4 edges: 2 per half, 2 in flight
      int e0 = colp[j + half];
      int e1 = colp[j + 2 + half];
      int c0 = e0 & 0x1FFFF, k0 = (e0 >> 17) - r0;
      int c1 = e1 & 0x1FFFF, k1 = (e1 >> 17) - r0;
      float2 y0 = __half22float2(Y2[(size_t)c0 * 32 + ch2]);
      float2 y1 = __half22float2(Y2[(size_t)c1 * 32 + ch2]);
      float2 a0 = lh[k0][ch2];
      a0.x += y0.x; a0.y += y0.y;
      lh[k0][ch2] = a0;
      float2 a1 = lh[k1][ch2];
      a1.x += y1.x; a1.y += y1.y;
      lh[k1][ch2] = a1;
    }
    for (; j + 2 <= q1; j += 2) {            // one edge per half
      int e0 = colp[j + half];
      int c0 = e0 & 0x1FFFF, k0 = (e0 >> 17) - r0;
      float2 y0 = __half22float2(Y2[(size_t)c0 * 32 + ch2]);
      float2 a0 = lh[k0][ch2];
      a0.x += y0.x; a0.y += y0.y;
      lh[k0][ch2] = a0;
    }
    if (j < q1) {                            // odd leftover: half0 only
      int e0 = colp[j];
      int c0 = e0 & 0x1FFFF, k0 = (e0 >> 17) - r0;
      float2 y0 = __half22float2(Y2[(size_t)c0 * 32 + ch2]);
      if (half == 0) {
        float2 a0 = lh[k0][ch2];
        a0.x += y0.x; a0.y += y0.y;
        lh[k0][ch2] = a0;
      }
    }
  }
}

// ---------------- aggregation, H=64: wave = 8 rows, block-major sweep -------
__global__ __launch_bounds__(256, 8) void agg64(const __half* __restrict__ Ys,
                                                const int* __restrict__ colp,
                                                const int* __restrict__ gseg,
                                                const float* __restrict__ dinv,
                                                const float* __restrict__ bias,
                                                __half* __restrict__ Xh,
                                                int N, int nbu) {
  __shared__ float2 lacc[4][2][NPW][32];
  int w = threadIdx.x >> 6, lane = threadIdx.x & 63;
  int half = lane >> 5, ch2 = lane & 31;
  int gw = blockIdx.x * 4 + w;
  int k = gw >> 6;                     // bucket (64 waves per bucket)
  int r0 = (gw & 63) * NPW;            // local row base
  int i0 = (k << BSHIFT) + r0;
  if (i0 >= N) return;
  const __half2* Y2 = (const __half2*)Ys;
  #pragma unroll
  for (int q = 0; q < NPW; ++q) lacc[w][half][q][ch2] = float2{0.f, 0.f};
  const int* gs = gseg + (size_t)k * (BROWS * NBLK);
  gather_flat(Y2, colp, gs, lacc[w][half], r0, half, ch2, nbu);
  if (half == 0) {
    float2 b2 = ((const float2*)bias)[ch2];
    #pragma unroll 1
    for (int q = 0; q < NPW; ++q) {
      int i = i0 + q;
      if (i >= N) break;
      float2 s0 = lacc[w][0][q][ch2];
      float2 s1 = lacc[w][1][q][ch2];
      float2 sy = __half22float2(Y2[(size_t)i * 32 + ch2]);   // self term
      float di = dinv[i];
      ((__half2*)Xh)[(size_t)i * 32 + ch2] =
          __floats2half2_rn(fmaxf(di * (s0.x + s1.x + sy.x) + b2.x, 0.f),
                            fmaxf(di * (s0.y + s1.y + sy.y) + b2.y, 0.f));
    }
  }
}

// ---------------- layer-4 aggregation fused with mean + W5 dot --------------
__global__ __launch_bounds__(256, 8) void agg64_final(const __half* __restrict__ Ys,
                                                      const int* __restrict__ colp,
                                                      const int* __restrict__ gseg,
                                                      const float* __restrict__ dinv,
                                                      const float* __restrict__ b4,
                                                      const float* __restrict__ W5,
                                                      float* __restrict__ h5,
                                                      float* __restrict__ red_m,
                                                      int N, int nbu) {
  __shared__ float2 lacc[4][2][NPW][32];
  __shared__ float2 sh2[4][32];
  int w = threadIdx.x >> 6, lane = threadIdx.x & 63;
  int half = lane >> 5, ch2 = lane & 31;
  int gw = blockIdx.x * 4 + w;
  int k = gw >> 6;
  int r0 = (gw & 63) * NPW;
  int i0 = (k << BSHIFT) + r0;
  const __half2* Y2 = (const __half2*)Ys;
  float2 w52 = ((const float2*)W5)[ch2];
  float2 b42 = ((const float2*)b4)[ch2];
  float2 msum = {0.f, 0.f};
  if (i0 < N) {
    #pragma unroll
    for (int q = 0; q < NPW; ++q) lacc[w][half][q][ch2] = float2{0.f, 0.f};
    const int* gs = gseg + (size_t)k * (BROWS * NBLK);
    gather_flat(Y2, colp, gs, lacc[w][half], r0, half, ch2, nbu);
    #pragma unroll 1
    for (int q = 0; q < NPW; ++q) {
      int i = i0 + q;
      if (i >= N) break;
      float2 s0 = lacc[w][0][q][ch2];        // both halves read both copies
      float2 s1 = lacc[w][1][q][ch2];
      float2 sy = __half22float2(Y2[(size_t)i * 32 + ch2]);
      float di = dinv[i];
      float hx = fmaxf(di * (s0.x + s1.x + sy.x) + b42.x, 0.f);
      float hy = fmaxf(di * (s0.y + s1.y + sy.y) + b42.y, 0.f);
      msum.x += hx;                    // duplicated across halves; half0 stores
      msum.y += hy;
      float p = waveSum(hx * w52.x + hy * w52.y);   // = 2 * dot (exact dup)
      if (lane == 0) h5[i] = di * p * 0.5f;
    }
  }
  if (half == 0) sh2[w][ch2] = msum;
  __syncthreads();
  if (threadIdx.x < 32) {
    int c = threadIdx.x;
    float tx = sh2[0][c].x + sh2[1][c].x + sh2[2][c].x + sh2[3][c].x;
    float ty = sh2[0][c].y + sh2[1][c].y + sh2[2][c].y + sh2[3][c].y;
    float* dst = &red_m[(blockIdx.x & 7) * 64];
    atomicAdd(&dst[2 * c], tx);
    atomicAdd(&dst[2 * c + 1], ty);
  }
}

// ---------------- scalar aggregation (layer 5): wave = 8 rows ---------------
// Lane-per-edge over the flat block ranges; 8-slot LDS atomics per wave.
__global__ __launch_bounds__(256, 8) void agg_scalar(const float* __restrict__ h5,
                                                     const int* __restrict__ colp,
                                                     const int* __restrict__ gseg,
                                                     const float* __restrict__ dinv,
                                                     const float* __restrict__ b5,
                                                     float* __restrict__ out,
                                                     int N, int nbu) {
  __shared__ float sacc[4][NPW];
  int w = threadIdx.x >> 6, lane = threadIdx.x & 63;
  int gw = blockIdx.x * 4 + w;
  int k = gw >> 6;
  int r0 = (gw & 63) * NPW;
  int i0 = (k << BSHIFT) + r0;
  if (i0 >= N) return;
  if (lane < NPW) sacc[w][lane] = 0.f;
  const int* gs = gseg + (size_t)k * (BROWS * NBLK);
  #pragma unroll 1
  for (int b = 0; b < nbu; ++b) {
    int q0 = gs[b * BROWS + r0];
    int q1 = gs[b * BROWS + r0 + NPW];
    for (int p = q0 + lane; p < q1; p += 64) {
      int v = colp[p];
      atomicAdd(&sacc[w][(v >> 17) - r0], h5[v & 0x1FFFF]);
    }
  }
  if (lane < NPW) {
    int i = i0 + lane;
    if (i < N) out[i] = dinv[i] * (sacc[w][lane] + h5[i]) + b5[0];
  }
}

// ---------------- heads: v and prob_nothing ----------------
__global__ void heads(const float* __restrict__ red_m, const float* __restrict__ Wv,
                      const float* __restrict__ bv, const float* __restrict__ Wdn,
                      const float* __restrict__ bdn, float* __restrict__ out, int N) {
  int lane = threadIdx.x;   // 64 threads
  float s = 0.f;
  #pragma unroll
  for (int r = 0; r < 8; ++r) s += red_m[r * 64 + lane];
  float xm = s / (float)N;
  float pv = waveSum(xm * Wv[lane]);
  float pd = waveSum(xm * Wdn[lane]);
  if (lane == 0) {
    out[N] = pd + bdn[0];       // prob_nothing logit
    out[N + 1] = pv + bv[0];    // value head (final output slot)
  }
}

// ---------------- masked softmax: 1 full pass + combine + write -------------
__global__ void smax_pass1(const float* __restrict__ out, const int* __restrict__ ready,
                           float* __restrict__ bm, float* __restrict__ bs, int N) {
  int i = blockIdx.x * 256 + threadIdx.x;
  bool valid = false;
  float l = -3e38f;
  if (i < N) { if (ready[i]) { valid = true; l = out[i]; } }
  else if (i == N) { valid = true; l = out[N]; }
  float m = waveMax(l);
  __shared__ float shm[4], shs[4];
  int wv = threadIdx.x >> 6;
  if ((threadIdx.x & 63) == 0) shm[wv] = m;
  __syncthreads();
  float bmax = fmaxf(fmaxf(shm[0], shm[1]), fmaxf(shm[2], shm[3]));
  float e = valid ? expf(l - bmax) : 0.f;
  float s = waveSum(e);
  if ((threadIdx.x & 63) == 0) shs[wv] = s;
  __syncthreads();
  if (threadIdx.x == 0) {
    bm[blockIdx.x] = bmax;
    bs[blockIdx.x] = shs[0] + shs[1] + shs[2] + shs[3];
  }
}

__global__ void smax_comb(const float* __restrict__ bm, const float* __restrict__ bs,
                          float* __restrict__ red, int NB) {
  int t = threadIdx.x;
  float m = -3e38f;
  for (int b = t; b < NB; b += 256) m = fmaxf(m, bm[b]);
  m = waveMax(m);
  __shared__ float shm[4], shs[4];
  if ((t & 63) == 0) shm[t >> 6] = m;
  __syncthreads();
  float M = fmaxf(fmaxf(shm[0], shm[1]), fmaxf(shm[2], shm[3]));
  float s = 0.f;
  for (int b = t; b < NB; b += 256) s += bs[b] * expf(bm[b] - M);
  s = waveSum(s);
  if ((t & 63) == 0) shs[t >> 6] = s;
  __syncthreads();
  if (t == 0) { red[0] = M; red[1] = shs[0] + shs[1] + shs[2] + shs[3]; }
}

__global__ void smax_write(float* __restrict__ out, const int* __restrict__ ready,
                           const float* __restrict__ red, int N) {
  float M = red[0];
  float S = red[1];
  int i = blockIdx.x * blockDim.x + threadIdx.x;
  if (i < N) {
    out[i] = ready[i] ? (expf(out[i] - M) / S) : 0.f;
  } else if (i == N) {
    out[N] = expf(out[N] - M) / S;
  }
}

// ---------------------------------------------------------------------------
extern "C" void kernel_launch(void* const* d_in, const int* in_sizes, int n_in,
                              void* d_out, int out_size, void* d_ws, size_t ws_size,
                              hipStream_t stream) {
  const float* x    = (const float*)d_in[0];
  const int*   ei   = (const int*)d_in[1];
  const int*   ready= (const int*)d_in[2];
  const float* W1   = (const float*)d_in[3];
  const float* b1   = (const float*)d_in[4];
  const float* W2   = (const float*)d_in[5];
  const float* b2   = (const float*)d_in[6];
  const float* W3   = (const float*)d_in[7];
  const float* b3   = (const float*)d_in[8];
  const float* W4   = (const float*)d_in[9];
  const float* b4   = (const float*)d_in[10];
  const float* W5   = (const float*)d_in[11];
  const float* b5   = (const float*)d_in[12];
  const float* Wdn  = (const float*)d_in[13];
  const float* bdn  = (const float*)d_in[14];
  const float* Wv   = (const float*)d_in[15];
  const float* bv   = (const float*)d_in[16];
  float* out = (float*)d_out;

  int N = in_sizes[2];          // ready is (N,1)
  int E = in_sizes[1] / 2;      // edge_index is (2,E)
  int nbkt = (N + BROWS - 1) >> BSHIFT;   // 196 for N=100000
  int nbu = (N + (1 << BLKSHIFT) - 1) >> BLKSHIFT;   // used col-blocks (7)

  // workspace carve (256B-aligned slices, byte-based)
  char* base = (char*)d_ws;
  size_t off = 0;
  auto allocB = [&](size_t bytes) -> void* {
    void* p = base + off;
    off += ((bytes + 255) / 256) * 256;
    return p;
  };
  size_t capBytes = (size_t)nbkt * CAP * 4;            // padded edge arrays
  float*    dinv       = (float*)allocB((size_t)N * 4);
  int*      gseg       = (int*)allocB((size_t)nbkt * BROWS * NBLK * 4);
  int*      bucket_fill= (int*)allocB(256 * 4);
  int*      colp       = (int*)allocB(capBytes);
  float*    h5         = (float*)allocB((size_t)N * 4);
  float*    red        = (float*)allocB(128 * 4);
  float*    red_m      = (float*)allocB(512 * 4);
  float*    bm         = (float*)allocB(512 * 4);
  float*    bs         = (float*)allocB(512 * 4);
  // Yb slot widened to hold eb (capBytes > N*64*2); eb dead before gemm1.
  size_t ybBytes = (size_t)N * 64 * 2;
  __half*   Yb         = (__half*)allocB(capBytes > ybBytes ? capBytes : ybBytes);
  __half*   Xh         = (__half*)allocB((size_t)N * 64 * 2);
  int*      eb         = (int*)Yb;
  (void)ws_size; (void)n_in; (void)out_size;

  int gN1 = (N + 1 + 255) / 256;
  int nwaves = (N + NPW - 1) / NPW;           // 12500
  int gAgg = (nwaves + 3) / 4;                // 3125 blocks, 4 waves each
  int gA = (E + ACHUNK - 1) / ACHUNK;
  int gG = (N + 63) / 64;                     // mfma gemm grid

  hipMemsetAsync(red_m, 0, 512 * 4, stream);
  bucket_init<<<1, 256, 0, stream>>>(bucket_fill, nbkt);
  bin_edges<<<gA, 256, 0, stream>>>(ei, bucket_fill, eb, E);
  csr_bucket<<<nbkt, 256, 0, stream>>>(eb, bucket_fill, gseg, dinv, colp, N);

  // layer 1 (K = 128, fp32 A converted in-register)
  gemm_f16<128, true><<<gG, 256, 0, stream>>>(x, W1, dinv, Yb, N);
  agg64<<<gAgg, 256, 0, stream>>>(Yb, colp, gseg, dinv, b1, Xh, N, nbu);
  // layers 2-3 (K = 64, fp16 A)
  gemm_f16<64, false><<<gG, 256, 0, stream>>>(Xh, W2, dinv, Yb, N);
  agg64<<<gAgg, 256, 0, stream>>>(Yb, colp, gseg, dinv, b2, Xh, N, nbu);
  gemm_f16<64, false><<<gG, 256, 0, stream>>>(Xh, W3, dinv, Yb, N);
  agg64<<<gAgg, 256, 0, stream>>>(Yb, colp, gseg, dinv, b3, Xh, N, nbu);
  // layer 4 gemm + fused agg/mean/W5-dot
  gemm_f16<64, false><<<gG, 256, 0, stream>>>(Xh, W4, dinv, Yb, N);
  agg64_final<<<gAgg, 256, 0, stream>>>(Yb, colp, gseg, dinv, b4, W5,
                                        h5, red_m, N, nbu);

  // layer 5 + heads
  agg_scalar<<<gAgg, 256, 0, stream>>>(h5, colp, gseg, dinv, b5, out, N, nbu);
  heads<<<1, 64, 0, stream>>>(red_m, Wv, bv, Wdn, bdn, out, N);

  // masked softmax over out[0..N]
  smax_pass1<<<gN1, 256, 0, stream>>>(out, ready, bm, bs, N);
  smax_comb<<<1, 256, 0, stream>>>(bm, bs, red, gN1);
  smax_write<<<gN1, 256, 0, stream>>>(out, ready, red, N);
}